// Round 1
// baseline (165.668 us; speedup 1.0000x reference)
//
#include <hip/hip_runtime.h>

#define BHW   25088
#define HW    3136
#define DD    64
#define KNEG  100
#define NBLK2 (BHW / 4)   // 6272 blocks, 4 rows (waves) per block

// ---------------------------------------------------------------------------
// Kernel 1: normalize x1 rows -> x1n (row-major (n,64)), compute positive[n].
// Tile transpose through LDS so global reads (d-major, stride HW) and writes
// (n-major) are both coalesced.
// ---------------------------------------------------------------------------
__global__ __launch_bounds__(256) void k1_normalize(
    const float* __restrict__ x1, const float* __restrict__ x2,
    float* __restrict__ x1n, float* __restrict__ pos)
{
    __shared__ float A[64][65];   // +1 pad: conflict-free column reads
    __shared__ float C[64][65];
    __shared__ float inv1[64];

    const int t   = threadIdx.x;
    const int col = t & 63;       // hw within tile / d on write phase
    const int qr  = t >> 6;       // 0..3
    const int blk = blockIdx.x;   // 392 = 8 * 49
    const int b    = blk / 49;
    const int tile = blk % 49;
    const int hw0  = tile * 64;

    const float* p1 = x1 + (size_t)b * DD * HW + hw0;
    const float* p2 = x2 + (size_t)b * DD * HW + hw0;

#pragma unroll
    for (int i = 0; i < 16; ++i) {
        const int row = i * 4 + qr;                  // d index
        A[row][col] = p1[(size_t)row * HW + col];    // coalesced 256B per wave-quarter
        C[row][col] = p2[(size_t)row * HW + col];
    }
    __syncthreads();

    if (t < 64) {
        // this thread owns row n = b*HW + hw0 + t
        float na = 0.f, nc = 0.f;
#pragma unroll
        for (int d = 0; d < 64; ++d) {
            const float a = A[d][t], c = C[d][t];
            na += a * a;
            nc += c * c;
        }
        const float r1 = 1.0f / fmaxf(sqrtf(na), 1e-12f);
        const float rc = 1.0f / fmaxf(sqrtf(nc), 1e-12f);
        float p = 0.f;
#pragma unroll
        for (int d = 0; d < 64; ++d) {
            p += expf(A[d][t] * r1 * C[d][t] * rc);  // TEMP == 1
        }
        inv1[t] = r1;
        pos[b * HW + hw0 + t] = p;
    }
    __syncthreads();

    // write x1n row-major: n fixed per 64-lane group, d = col -> coalesced
    float* outbase = x1n + (size_t)(b * HW + hw0) * DD;
#pragma unroll
    for (int i = 0; i < 16; ++i) {
        const int nl = i * 4 + qr;
        outbase[(size_t)nl * DD + col] = A[col][nl] * inv1[nl];
    }
}

// ---------------------------------------------------------------------------
// Kernel 2: negative[n] = sum_k exp(dot64(x1n[n], x1n[idx[n,k]])).
// One wave per n; lanes = (kk=lane>>4 in 0..3) x (ld=lane&15 float4-chunk).
// Each gathered row is read as 16 lanes x float4 = one contiguous 256B burst.
// Block partial losses -> partials[blockIdx].
// ---------------------------------------------------------------------------
__global__ __launch_bounds__(256) void k2_negative(
    const float* __restrict__ x1n, const int* __restrict__ neg_idx,
    const float* __restrict__ pos, float* __restrict__ partials)
{
    __shared__ float4 q[4][16];   // 4 query rows per block
    __shared__ float  wpart[4];

    const int t  = threadIdx.x;
    const int w  = t >> 6;        // wave id 0..3
    const int l  = t & 63;
    const int n0 = blockIdx.x * 4;

    const float4* x4 = (const float4*)x1n;

    if (t < 64) {
        ((float4*)q)[t] = x4[(size_t)n0 * 16 + t];   // q[w][ld] <- row (n0+w)
    }
    __syncthreads();

    const int n  = n0 + w;
    const int kk = l >> 4;        // which of 4 concurrent negatives
    const int ld = l & 15;        // float4 chunk within row
    const int* idxp = neg_idx + (size_t)n * KNEG;
    const float4 qq = q[w][ld];

    float acc = 0.f;
#pragma unroll 1
    for (int i = 0; i < 25; ++i) {
        const int idx = idxp[i * 4 + kk];
        const float4 v = x4[(size_t)idx * 16 + ld];
        float s = v.x * qq.x + v.y * qq.y + v.z * qq.z + v.w * qq.w;
        s += __shfl_xor(s, 1);
        s += __shfl_xor(s, 2);
        s += __shfl_xor(s, 4);
        s += __shfl_xor(s, 8);     // all 16 lanes of group hold full dot
        acc += (ld == 0) ? expf(s) : 0.0f;
    }
    // combine the 4 group leaders (lanes 0,16,32,48; others hold 0)
    acc += __shfl_xor(acc, 16);
    acc += __shfl_xor(acc, 32);

    if (l == 0) {
        const float p = pos[n];
        wpart[w] = log1pf(acc / p);   // log(p+neg) - log(p)
    }
    __syncthreads();
    if (t == 0) {
        partials[blockIdx.x] = wpart[0] + wpart[1] + wpart[2] + wpart[3];
    }
}

// ---------------------------------------------------------------------------
// Kernel 3: reduce 6272 partials -> mean loss scalar.
// ---------------------------------------------------------------------------
__global__ __launch_bounds__(256) void k3_reduce(
    const float* __restrict__ partials, float* __restrict__ out)
{
    __shared__ float s[256];
    const int t = threadIdx.x;
    float a = 0.f;
    for (int i = t; i < NBLK2; i += 256) a += partials[i];
    s[t] = a;
    __syncthreads();
    for (int off = 128; off > 0; off >>= 1) {
        if (t < off) s[t] += s[t + off];
        __syncthreads();
    }
    if (t == 0) out[0] = s[0] * (1.0f / (float)BHW);
}

extern "C" void kernel_launch(void* const* d_in, const int* in_sizes, int n_in,
                              void* d_out, int out_size, void* d_ws, size_t ws_size,
                              hipStream_t stream)
{
    const float* x1  = (const float*)d_in[0];
    const float* x2  = (const float*)d_in[1];
    const int*   neg = (const int*)d_in[2];
    float* out = (float*)d_out;

    char* ws = (char*)d_ws;
    float* x1n      = (float*)ws;                                   // 25088*64 f32 (6.42 MB)
    float* pos      = (float*)(ws + (size_t)BHW * DD * 4);          // 25088 f32
    float* partials = (float*)(ws + (size_t)BHW * DD * 4 + BHW * 4);// 6272 f32

    k1_normalize<<<8 * 49, 256, 0, stream>>>(x1, x2, x1n, pos);
    k2_negative<<<NBLK2, 256, 0, stream>>>(x1n, neg, pos, partials);
    k3_reduce<<<1, 256, 0, stream>>>(partials, out);
}

// Round 2
// 121.206 us; speedup vs baseline: 1.3668x; 1.3668x over previous
//
#include <hip/hip_runtime.h>

#define BHW   25088
#define HW    3136
#define DD    64
#define KNEG  100
#define NBLK2 (BHW / 4)   // 6272 blocks, 4 waves (n's) per block

// ---------------------------------------------------------------------------
// Kernel 1: normalize x1 rows -> x1n (row-major (n,64)), compute positive[n].
// Tile transpose through LDS; ALL 256 threads active in the compute phase:
// wave w owns rows w*16..w*16+15, lane chunk c=l>>4 owns d in [16c,16c+16).
// ---------------------------------------------------------------------------
__global__ __launch_bounds__(256) void k1_normalize(
    const float* __restrict__ x1, const float* __restrict__ x2,
    float* __restrict__ x1n, float* __restrict__ pos)
{
    __shared__ float A[64][65];   // +1 pad: conflict-free column reads
    __shared__ float C[64][65];
    __shared__ float inv1[64];

    const int t   = threadIdx.x;
    const int col = t & 63;       // hw within tile (stage) / d (write phase)
    const int qr  = t >> 6;       // 0..3
    const int b    = blockIdx.x / 49;
    const int tile = blockIdx.x % 49;
    const int hw0  = tile * 64;

    const float* p1 = x1 + (size_t)b * DD * HW + hw0;
    const float* p2 = x2 + (size_t)b * DD * HW + hw0;

#pragma unroll
    for (int i = 0; i < 16; ++i) {
        const int row = i * 4 + qr;                  // d index
        A[row][col] = p1[(size_t)row * HW + col];    // coalesced 256B
        C[row][col] = p2[(size_t)row * HW + col];
    }
    __syncthreads();

    // phase 2: 256 threads = 64 rows x 4 d-chunks
    const int l = t & 63;
    const int r = qr * 16 + (l & 15);   // row within tile (this wave's 16 rows)
    const int c = l >> 4;               // d-chunk 0..3

    float na = 0.f, nc = 0.f;
#pragma unroll
    for (int j = 0; j < 16; ++j) {
        const int d = c * 16 + j;
        const float a = A[d][r], cc = C[d][r];
        na += a * a;
        nc += cc * cc;
    }
    na += __shfl_xor(na, 16); na += __shfl_xor(na, 32);
    nc += __shfl_xor(nc, 16); nc += __shfl_xor(nc, 32);
    const float r1 = 1.0f / fmaxf(sqrtf(na), 1e-12f);
    const float rc = 1.0f / fmaxf(sqrtf(nc), 1e-12f);
    const float scale = r1 * rc;

    float p = 0.f;
#pragma unroll
    for (int j = 0; j < 16; ++j) {
        const int d = c * 16 + j;
        p += __expf(A[d][r] * C[d][r] * scale);   // TEMP == 1
    }
    p += __shfl_xor(p, 16); p += __shfl_xor(p, 32);

    if (c == 0) {
        pos[b * HW + hw0 + r] = p;
        inv1[r] = r1;
    }
    __syncthreads();

    // write x1n row-major: n fixed per 64-lane stride group, d = col -> coalesced
    float* outbase = x1n + (size_t)(b * HW + hw0) * DD;
#pragma unroll
    for (int i = 0; i < 16; ++i) {
        const int nl = i * 4 + qr;
        outbase[(size_t)nl * DD + col] = A[col][nl] * inv1[nl];
    }
}

// ---------------------------------------------------------------------------
// Kernel 2: negative[n] = sum_k exp(dot64(x1n[n], x1n[idx[n,k]])).
// One wave per n. 4 lanes per negative (g=l>>2 picks the negative, c=l&3 the
// float4 slot), 16 negatives per iteration, 7 iterations (last masked).
// Gather instruction j: 4-lane group reads row*256 + j*64 + c*16 -> each
// group covers one contiguous 64B line; 16 lines per instruction, fully
// coalesced. Dot reduced with just 2 shfl_xor. exp on all lanes (4x
// redundant, folded out by the group-level butterfly).
// ---------------------------------------------------------------------------
__global__ __launch_bounds__(256) void k2_negative(
    const float* __restrict__ x1n, const int* __restrict__ neg_idx,
    const float* __restrict__ pos, float* __restrict__ partials)
{
    __shared__ float wpart[4];

    const int t = threadIdx.x;
    const int w = t >> 6;         // wave id 0..3
    const int l = t & 63;
    const int n = blockIdx.x * 4 + w;
    const int g = l >> 2;         // negative group 0..15
    const int c = l & 3;          // float4 slot within group

    const float4* x4 = (const float4*)x1n;
    const int* idxp = neg_idx + (size_t)n * KNEG;

    // query fragments: lane needs float4 indices {c, 4+c, 8+c, 12+c}
    const size_t qb = (size_t)n * 16;
    const float4 q0 = x4[qb + 0 * 4 + c];
    const float4 q1 = x4[qb + 1 * 4 + c];
    const float4 q2 = x4[qb + 2 * 4 + c];
    const float4 q3 = x4[qb + 3 * 4 + c];

    float acc = 0.f;
#pragma unroll
    for (int i = 0; i < 7; ++i) {
        const int kidx = i * 16 + g;
        const int kc   = kidx < KNEG ? kidx : (KNEG - 1);  // clamp (masked below)
        const int row  = idxp[kc];
        const size_t base = (size_t)row * 16;
        const float4 v0 = x4[base + 0 * 4 + c];
        const float4 v1 = x4[base + 1 * 4 + c];
        const float4 v2 = x4[base + 2 * 4 + c];
        const float4 v3 = x4[base + 3 * 4 + c];

        float s = v0.x * q0.x + v0.y * q0.y + v0.z * q0.z + v0.w * q0.w;
        s += v1.x * q1.x + v1.y * q1.y + v1.z * q1.z + v1.w * q1.w;
        s += v2.x * q2.x + v2.y * q2.y + v2.z * q2.z + v2.w * q2.w;
        s += v3.x * q3.x + v3.y * q3.y + v3.z * q3.z + v3.w * q3.w;

        s += __shfl_xor(s, 1);
        s += __shfl_xor(s, 2);     // all 4 lanes of group hold full dot

        const float e = __expf(s); // TEMP == 1
        acc += (kidx < KNEG) ? e : 0.f;
    }
    // within a 4-lane group all lanes hold identical acc; butterfly over the
    // 16 groups (masks 4,8,16,32) -> every lane holds negative[n]
    acc += __shfl_xor(acc, 4);
    acc += __shfl_xor(acc, 8);
    acc += __shfl_xor(acc, 16);
    acc += __shfl_xor(acc, 32);

    if (l == 0) {
        wpart[w] = log1pf(acc / pos[n]);   // log(p+neg) - log(p)
    }
    __syncthreads();
    if (t == 0) {
        partials[blockIdx.x] = wpart[0] + wpart[1] + wpart[2] + wpart[3];
    }
}

// ---------------------------------------------------------------------------
// Kernel 3: reduce 6272 partials -> mean loss scalar.
// ---------------------------------------------------------------------------
__global__ __launch_bounds__(256) void k3_reduce(
    const float* __restrict__ partials, float* __restrict__ out)
{
    __shared__ float s[256];
    const int t = threadIdx.x;
    float a = 0.f;
    for (int i = t; i < NBLK2; i += 256) a += partials[i];
    s[t] = a;
    __syncthreads();
    for (int off = 128; off > 0; off >>= 1) {
        if (t < off) s[t] += s[t + off];
        __syncthreads();
    }
    if (t == 0) out[0] = s[0] * (1.0f / (float)BHW);
}

extern "C" void kernel_launch(void* const* d_in, const int* in_sizes, int n_in,
                              void* d_out, int out_size, void* d_ws, size_t ws_size,
                              hipStream_t stream)
{
    const float* x1  = (const float*)d_in[0];
    const float* x2  = (const float*)d_in[1];
    const int*   neg = (const int*)d_in[2];
    float* out = (float*)d_out;

    char* ws = (char*)d_ws;
    float* x1n      = (float*)ws;                                   // 25088*64 f32 (6.42 MB)
    float* pos      = (float*)(ws + (size_t)BHW * DD * 4);          // 25088 f32
    float* partials = (float*)(ws + (size_t)BHW * DD * 4 + BHW * 4);// 6272 f32

    k1_normalize<<<8 * 49, 256, 0, stream>>>(x1, x2, x1n, pos);
    k2_negative<<<NBLK2, 256, 0, stream>>>(x1n, neg, pos, partials);
    k3_reduce<<<1, 256, 0, stream>>>(partials, out);
}